// Round 10
// baseline (3593.144 us; speedup 1.0000x reference)
//
#include <hip/hip_runtime.h>
#include <math.h>

#define T_DIM 1024
#define NP    2048
#define NB    1024
#define NITER 25
#define NSQ   5
#define NPI   8
#define LAM0  0.1f
#define EPS_W 1e-10f

typedef float    f32x4 __attribute__((ext_vector_type(4)));
typedef _Float16 f16x8 __attribute__((ext_vector_type(8)));
typedef _Float16 f16x4 __attribute__((ext_vector_type(4)));

__device__ __forceinline__ void gload16(const void* g, void* l) {
  __builtin_amdgcn_global_load_lds((const __attribute__((address_space(1))) unsigned int*)g,
                                   (__attribute__((address_space(3))) unsigned int*)l, 16, 0, 0);
}

// =====================================================================
// Double-buffered 128x128-tile dual-acc 3-pass split-f16 core (BK=32).
// 512 thr = 8 waves (2n x 4p), wave tile 64x32. LDS 2 buf x 4 arr x 8KB = 64KB.
// (R9-proven; ~40 us/dispatch — m97-plateau bound.)
// =====================================================================
__device__ __forceinline__ void mm3_db(
    const _Float16* __restrict__ Ah, const _Float16* __restrict__ Al,
    const _Float16* __restrict__ Bh, const _Float16* __restrict__ Bl,
    int ldk, int n0, int p0, int kb0, int nsteps,   // nsteps = K/32
    f32x4 acc0[4][2], f32x4 acc1[4][2])
{
  __shared__ __align__(16) _Float16 sm[2][4][4096];
  const int tid = threadIdx.x;
  const int lane = tid & 63, wave = tid >> 6;
  const int quad = lane >> 4, rl = lane & 15;
  const int wn = (wave >> 2) * 64, wp = (wave & 3) * 32;
  const int kc = tid >> 7, row = tid & 127;
  const int lbe = wave * 512;
#pragma unroll
  for (int i = 0; i < 4; i++)
#pragma unroll
    for (int j = 0; j < 2; j++) { acc0[i][j] = (f32x4)0.0f; acc1[i][j] = (f32x4)0.0f; }

  {
    size_t ga = (size_t)(n0 + row) * ldk + kb0 + kc * 8;
    size_t gb = (size_t)(p0 + row) * ldk + kb0 + kc * 8;
    gload16(Ah + ga, &sm[0][0][lbe]);
    gload16(Al + ga, &sm[0][1][lbe]);
    gload16(Bh + gb, &sm[0][2][lbe]);
    gload16(Bl + gb, &sm[0][3][lbe]);
  }
  for (int s = 0; s < nsteps; s++) {
    const int cur = s & 1;
    __syncthreads();
    if (s + 1 < nsteps) {
      const int nxt = cur ^ 1;
      const int kb = kb0 + (s + 1) * 32;
      size_t ga = (size_t)(n0 + row) * ldk + kb + kc * 8;
      size_t gb = (size_t)(p0 + row) * ldk + kb + kc * 8;
      gload16(Ah + ga, &sm[nxt][0][lbe]);
      gload16(Al + ga, &sm[nxt][1][lbe]);
      gload16(Bh + gb, &sm[nxt][2][lbe]);
      gload16(Bl + gb, &sm[nxt][3][lbe]);
    }
    f16x8 a_h[4], a_l[4], b_h[2], b_l[2];
#pragma unroll
    for (int t = 0; t < 4; t++) {
      int ar = (quad * 128 + wn + t * 16 + rl) * 8;
      a_h[t] = *(const f16x8*)&sm[cur][0][ar];
      a_l[t] = *(const f16x8*)&sm[cur][1][ar];
    }
#pragma unroll
    for (int t = 0; t < 2; t++) {
      int bp = (quad * 128 + wp + t * 16 + rl) * 8;
      b_h[t] = *(const f16x8*)&sm[cur][2][bp];
      b_l[t] = *(const f16x8*)&sm[cur][3][bp];
    }
#pragma unroll
    for (int mt = 0; mt < 4; mt++)
#pragma unroll
      for (int nt = 0; nt < 2; nt++)
        acc0[mt][nt] = __builtin_amdgcn_mfma_f32_16x16x32_f16(a_h[mt], b_h[nt], acc0[mt][nt], 0, 0, 0);
#pragma unroll
    for (int mt = 0; mt < 4; mt++)
#pragma unroll
      for (int nt = 0; nt < 2; nt++)
        acc1[mt][nt] = __builtin_amdgcn_mfma_f32_16x16x32_f16(a_l[mt], b_h[nt], acc1[mt][nt], 0, 0, 0);
#pragma unroll
    for (int mt = 0; mt < 4; mt++)
#pragma unroll
      for (int nt = 0; nt < 2; nt++)
        acc1[mt][nt] = __builtin_amdgcn_mfma_f32_16x16x32_f16(a_h[mt], b_l[nt], acc1[mt][nt], 0, 0, 0);
  }
}

// ---- main-loop GEMM: part[z] = Cp x DtD, splitK=4, XCD-swizzled ----
__global__ __launch_bounds__(512, 4) void k_mm(const _Float16* __restrict__ Ch, const _Float16* __restrict__ Cl,
                                               const _Float16* __restrict__ H, const _Float16* __restrict__ Ee,
                                               float* __restrict__ part) {
  const int b = blockIdx.x;
  const int xcd = b & 7, q = b >> 3;
  const int pt = xcd * 2 + (q & 1);
  const int ny = (q >> 1) & 7;
  const int z  = q >> 4;
  f32x4 acc0[4][2], acc1[4][2];
  const int n0 = ny * 128, p0 = pt * 128;
  mm3_db(Ch, Cl, H, Ee, 2048, n0, p0, z * 512, 16, acc0, acc1);
  const int lane = threadIdx.x & 63, wave = threadIdx.x >> 6;
  const int quad = lane >> 4, rl = lane & 15;
  const int wn = (wave >> 2) * 64, wp = (wave & 3) * 32;
  float* op = part + (size_t)z * NB * NP;
#pragma unroll
  for (int mt = 0; mt < 4; mt++)
#pragma unroll
    for (int nt = 0; nt < 2; nt++) {
      const int p = p0 + wp + nt * 16 + rl;
      const size_t rb = (size_t)(n0 + wn + mt * 16 + quad * 4) * NP + p;
#pragma unroll
      for (int r = 0; r < 4; r++)
        op[rb + (size_t)r * NP] = acc0[mt][nt][r] + acc1[mt][nt][r] * (1.f / 4096.f);
    }
}

// ---- epilogue: XCD-local, 1024 blocks x 8 elems/thread ----
__global__ __launch_bounds__(256) void k_epi(const float* __restrict__ part,
    const float* __restrict__ DtY_, const float* __restrict__ CcIn,
    const _Float16* __restrict__ ChIn, const _Float16* __restrict__ ClIn,
    const float* __restrict__ Lptr, const float* __restrict__ thrM, float tc,
    float* __restrict__ CcOut, _Float16* __restrict__ ChOut, _Float16* __restrict__ ClOut) {
  const int b = blockIdx.x;            // 1024 blocks
  const int xcd = b & 7, r_ = b >> 3;  // r_ 0..127
  const int pt = xcd * 2 + (r_ & 1);   // matches k_mm's pt->XCD map
  const int nc = r_ >> 1;              // 0..63 (16-row slabs)
  const int tid = threadIdx.x;
  const int rowi = nc * 16 + (tid >> 4);
  const int col = pt * 128 + (tid & 15) * 8;
  const size_t g = (size_t)rowi * NP + col;
  const float Lv = Lptr[0];
  const float thr_s = Lv * LAM0;
#pragma unroll
  for (int h4 = 0; h4 < 2; h4++) {
    const size_t gg = g + h4 * 4;
    float ps[4], dy[4], cc[4], th[4];
    *(float4*)ps = *(const float4*)(part + gg);
#pragma unroll
    for (int z = 1; z < 4; z++) {
      float t[4];
      *(float4*)t = *(const float4*)(part + (size_t)z * NB * NP + gg);
#pragma unroll
      for (int j = 0; j < 4; j++) ps[j] += t[j];
    }
    *(float4*)dy = *(const float4*)(DtY_ + gg);
    *(float4*)cc = *(const float4*)(CcIn + gg);
    f16x4 chv = *(const f16x4*)(ChIn + gg);
    f16x4 clv = *(const f16x4*)(ClIn + gg);
    if (thrM) { *(float4*)th = *(const float4*)(thrM + gg); }
    float cn[4];
    f16x4 ho, lo;
#pragma unroll
    for (int j = 0; j < 4; j++) {
      float grad = ps[j] - dy[j];
      float cp = (float)chv[j] + (float)clv[j] * (1.f / 4096.f);
      float z = cp - Lv * grad;
      float t2 = thrM ? th[j] : thr_s;
      float az = fabsf(z) - t2;
      float v = az > 0.f ? copysignf(az, z) : 0.f;
      cn[j] = v;
      float cpn = fmaf(tc, v - cc[j], v);
      _Float16 h = (_Float16)cpn;
      ho[j] = h;
      lo[j] = (_Float16)((cpn - (float)h) * 4096.f);
    }
    *(float4*)(CcOut + gg) = *(float4*)cn;
    *(f16x4*)(ChOut + gg) = ho;
    *(f16x4*)(ClOut + gg) = lo;
  }
}

// =====================================================================
// 64x64-tile core for pre-loop kernels. BK=64 (LDS 4 x 8 KB = 32 KB)
// -> 4 blocks/CU at <=128 combined regs.
// =====================================================================
__device__ __forceinline__ void mm3c(
    const _Float16* __restrict__ Ah, const _Float16* __restrict__ Al,
    const _Float16* __restrict__ Bh, const _Float16* __restrict__ Bl,
    int ldk, int n0, int p0, int nsteps,            // nsteps = K/64
    f32x4 acc0[2][2], f32x4 acc1[2][2])
{
  __shared__ __align__(16) _Float16 sAh[4096], sAl[4096], sBh[4096], sBl[4096];
  const int tid = threadIdx.x;
  const int lane = tid & 63, w = tid >> 6;
  const int quad = lane >> 4, rl = lane & 15;
  const int wm = (w >> 1) * 32, wp = (w & 1) * 32;
#pragma unroll
  for (int i = 0; i < 2; i++)
#pragma unroll
    for (int j = 0; j < 2; j++) { acc0[i][j] = (f32x4)0.0f; acc1[i][j] = (f32x4)0.0f; }

  for (int s = 0; s < nsteps; s++) {
    const int kb = s * 64;
    if (s) __syncthreads();
#pragma unroll
    for (int i = 0; i < 2; i++) {
      int slot = i * 256 + w * 64 + lane;       // 0..511
      int kc = slot >> 6, row = slot & 63;      // kc 0..7
      int lb = (i * 256 + w * 64) * 8;
      size_t ga = (size_t)(n0 + row) * ldk + kb + kc * 8;
      size_t gb = (size_t)(p0 + row) * ldk + kb + kc * 8;
      gload16(Ah + ga, sAh + lb);
      gload16(Al + ga, sAl + lb);
      gload16(Bh + gb, sBh + lb);
      gload16(Bl + gb, sBl + lb);
    }
    __syncthreads();
#pragma unroll
    for (int kk = 0; kk < 2; kk++) {
      const int kc = kk * 4 + quad;
      f16x8 a_h[2], a_l[2], b_h[2], b_l[2];
#pragma unroll
      for (int t = 0; t < 2; t++) {
        int ar = wm + t * 16 + rl;
        int bp = wp + t * 16 + rl;
        a_h[t] = *(const f16x8*)&sAh[(kc * 64 + ar) * 8];
        a_l[t] = *(const f16x8*)&sAl[(kc * 64 + ar) * 8];
        b_h[t] = *(const f16x8*)&sBh[(kc * 64 + bp) * 8];
        b_l[t] = *(const f16x8*)&sBl[(kc * 64 + bp) * 8];
      }
#pragma unroll
      for (int mt = 0; mt < 2; mt++)
#pragma unroll
        for (int nt = 0; nt < 2; nt++) {
          acc0[mt][nt] = __builtin_amdgcn_mfma_f32_16x16x32_f16(a_h[mt], b_h[nt], acc0[mt][nt], 0, 0, 0);
          acc1[mt][nt] = __builtin_amdgcn_mfma_f32_16x16x32_f16(a_l[mt], b_h[nt], acc1[mt][nt], 0, 0, 0);
          acc1[mt][nt] = __builtin_amdgcn_mfma_f32_16x16x32_f16(a_h[mt], b_l[nt], acc1[mt][nt], 0, 0, 0);
        }
    }
  }
}

// ---- DtD (2048x2048, K=1024): emits H/Ee split. grid 1024. ----
__global__ __launch_bounds__(256, 4) void k_dtd(const _Float16* __restrict__ Dth, const _Float16* __restrict__ Dtl,
                                                _Float16* __restrict__ H, _Float16* __restrict__ Ee) {
  const int b = blockIdx.x;
  const int xcd = b & 7, i4 = b >> 3;
  const int ny = i4 >> 2, pt = xcd * 4 + (i4 & 3);
  const int n0 = ny * 64, p0 = pt * 64;
  f32x4 acc0[2][2], acc1[2][2];
  mm3c(Dth, Dtl, Dth, Dtl, 1024, n0, p0, 16, acc0, acc1);
  const int lane = threadIdx.x & 63, w = threadIdx.x >> 6;
  const int quad = lane >> 4, rl = lane & 15;
  const int wm = (w >> 1) * 32, wp = (w & 1) * 32;
#pragma unroll
  for (int mt = 0; mt < 2; mt++)
#pragma unroll
    for (int nt = 0; nt < 2; nt++) {
      const int p = p0 + wp + nt * 16 + rl;
      const size_t rb = (size_t)(n0 + wm + mt * 16 + quad * 4) * NP + p;
#pragma unroll
      for (int r = 0; r < 4; r++) {
        const size_t idx = rb + (size_t)r * NP;
        float v = acc0[mt][nt][r] + acc1[mt][nt][r] * (1.f / 4096.f);
        _Float16 h = (_Float16)v;
        H[idx] = h;
        Ee[idx] = (_Float16)((v - (float)h) * 4096.f);
      }
    }
}

// ---- G = D x D^T (1024x1024, K=2048) fp32 + ||G||_F^2. grid 256. ----
__global__ __launch_bounds__(256, 4) void k_g(const _Float16* __restrict__ Dh, const _Float16* __restrict__ Dl,
                                              float* __restrict__ G, float* __restrict__ ss0) {
  const int b = blockIdx.x;
  const int xcd = b & 7, i4 = b >> 3;
  const int ny = i4 >> 1, pt = xcd * 2 + (i4 & 1);
  const int n0 = ny * 64, p0 = pt * 64;
  f32x4 acc0[2][2], acc1[2][2];
  mm3c(Dh, Dl, Dh, Dl, 2048, n0, p0, 32, acc0, acc1);
  const int tid = threadIdx.x;
  const int lane = tid & 63, w = tid >> 6;
  const int quad = lane >> 4, rl = lane & 15;
  const int wm = (w >> 1) * 32, wp = (w & 1) * 32;
  float ssl = 0.f;
#pragma unroll
  for (int mt = 0; mt < 2; mt++)
#pragma unroll
    for (int nt = 0; nt < 2; nt++) {
      const int p = p0 + wp + nt * 16 + rl;
      const size_t rb = (size_t)(n0 + wm + mt * 16 + quad * 4) * 1024 + p;
#pragma unroll
      for (int r = 0; r < 4; r++) {
        float v = acc0[mt][nt][r] + acc1[mt][nt][r] * (1.f / 4096.f);
        G[rb + (size_t)r * 1024] = v;
        ssl = fmaf(v, v, ssl);
      }
    }
  __shared__ float red[256];
  red[tid] = ssl; __syncthreads();
  for (int off = 128; off > 0; off >>= 1) {
    if (tid < off) red[tid] += red[tid + off];
    __syncthreads();
  }
  if (tid == 0) atomicAdd(ss0, red[0]);
}

// ---- DtY[n][p] (1024x2048, K=1024) fp32. grid 512. ----
__global__ __launch_bounds__(256, 4) void k_dty(const _Float16* __restrict__ Yth, const _Float16* __restrict__ Ytl,
                                                const _Float16* __restrict__ Dth, const _Float16* __restrict__ Dtl,
                                                float* __restrict__ DtY_) {
  const int b = blockIdx.x;
  const int xcd = b & 7, i4 = b >> 3;
  const int ny = i4 >> 2, pt = xcd * 4 + (i4 & 3);
  const int n0 = ny * 64, p0 = pt * 64;
  f32x4 acc0[2][2], acc1[2][2];
  mm3c(Yth, Ytl, Dth, Dtl, 1024, n0, p0, 16, acc0, acc1);
  const int lane = threadIdx.x & 63, w = threadIdx.x >> 6;
  const int quad = lane >> 4, rl = lane & 15;
  const int wm = (w >> 1) * 32, wp = (w & 1) * 32;
#pragma unroll
  for (int mt = 0; mt < 2; mt++)
#pragma unroll
    for (int nt = 0; nt < 2; nt++) {
      const int p = p0 + wp + nt * 16 + rl;
      const size_t rb = (size_t)(n0 + wm + mt * 16 + quad * 4) * NP + p;
#pragma unroll
      for (int r = 0; r < 4; r++)
        DtY_[rb + (size_t)r * NP] = acc0[mt][nt][r] + acc1[mt][nt][r] * (1.f / 4096.f);
    }
}

// ---- f16 squaring, fused normalize + x4096 lift + f16 out. grid 256, BK=64. ----
__global__ __launch_bounds__(256, 4) void k_sqf(const _Float16* __restrict__ Min, const float* __restrict__ ssPrev,
                                                _Float16* __restrict__ Mout, float* __restrict__ ssNext,
                                                float invfac) {
  __shared__ __align__(16) _Float16 sA[4096], sB[4096];
  const int b = blockIdx.x;
  const int xcd = b & 7, i4 = b >> 3;
  const int ny = i4 >> 1, pt = xcd * 2 + (i4 & 1);
  const int n0 = ny * 64, p0 = pt * 64;
  const int tid = threadIdx.x;
  const int lane = tid & 63, w = tid >> 6;
  const int quad = lane >> 4, rl = lane & 15;
  const int wm = (w >> 1) * 32, wp = (w & 1) * 32;
  f32x4 acc[2][2];
#pragma unroll
  for (int i = 0; i < 2; i++)
#pragma unroll
    for (int j = 0; j < 2; j++) acc[i][j] = (f32x4)0.0f;

  for (int s = 0; s < 16; s++) {
    const int kb = s * 64;
    if (s) __syncthreads();
#pragma unroll
    for (int i = 0; i < 2; i++) {
      int slot = i * 256 + w * 64 + lane;
      int kc = slot >> 6, row = slot & 63;
      int lb = (i * 256 + w * 64) * 8;
      gload16(Min + (size_t)(n0 + row) * 1024 + kb + kc * 8, sA + lb);
      gload16(Min + (size_t)(p0 + row) * 1024 + kb + kc * 8, sB + lb);
    }
    __syncthreads();
#pragma unroll
    for (int kk = 0; kk < 2; kk++) {
      const int kc = kk * 4 + quad;
      f16x8 a[2], bb[2];
#pragma unroll
      for (int t = 0; t < 2; t++) {
        a[t]  = *(const f16x8*)&sA[(kc * 64 + wm + t * 16 + rl) * 8];
        bb[t] = *(const f16x8*)&sB[(kc * 64 + wp + t * 16 + rl) * 8];
      }
#pragma unroll
      for (int mt = 0; mt < 2; mt++)
#pragma unroll
        for (int nt = 0; nt < 2; nt++)
          acc[mt][nt] = __builtin_amdgcn_mfma_f32_16x16x32_f16(a[mt], bb[nt], acc[mt][nt], 0, 0, 0);
    }
  }
  const float inv = invfac / ssPrev[0];
  float ssl = 0.f;
#pragma unroll
  for (int mt = 0; mt < 2; mt++)
#pragma unroll
    for (int nt = 0; nt < 2; nt++) {
      const int p = p0 + wp + nt * 16 + rl;
      const size_t rb = (size_t)(n0 + wm + mt * 16 + quad * 4) * 1024 + p;
#pragma unroll
      for (int r = 0; r < 4; r++) {
        float v = acc[mt][nt][r] * inv;
        Mout[rb + (size_t)r * 1024] = (_Float16)(v * 4096.f);
        ssl = fmaf(v, v, ssl);
      }
    }
  __syncthreads();
  float* red = (float*)sA;
  red[tid] = ssl; __syncthreads();
  for (int off = 128; off > 0; off >>= 1) {
    if (tid < off) red[tid] += red[tid + off];
    __syncthreads();
  }
  if (tid == 0) atomicAdd(ssNext, red[0]);
}

// ---- fp32 -> f16 (h, l*4096) split ----
__global__ __launch_bounds__(256) void k_split(const float* __restrict__ src, _Float16* __restrict__ H,
                                               _Float16* __restrict__ L, int n4) {
  int g = blockIdx.x * 256 + threadIdx.x;
  if (g < n4) {
    float4 v = ((const float4*)src)[g];
    float vv[4] = {v.x, v.y, v.z, v.w};
    f16x4 h, l;
#pragma unroll
    for (int j = 0; j < 4; j++) {
      _Float16 hh = (_Float16)vv[j];
      h[j] = hh;
      l[j] = (_Float16)((vv[j] - (float)hh) * 4096.f);
    }
    ((f16x4*)H)[g] = h;
    ((f16x4*)L)[g] = l;
  }
}

// ---- fp32 -> f16 with scale ----
__global__ __launch_bounds__(256) void k_h16(const float* __restrict__ src, _Float16* __restrict__ dst,
                                             int n4, float scale) {
  int g = blockIdx.x * 256 + threadIdx.x;
  if (g < n4) {
    float4 v = ((const float4*)src)[g];
    f16x4 h;
    h[0] = (_Float16)(v.x * scale); h[1] = (_Float16)(v.y * scale);
    h[2] = (_Float16)(v.z * scale); h[3] = (_Float16)(v.w * scale);
    ((f16x4*)dst)[g] = h;
  }
}

// ---- fp32 transpose 64x64 tiles ----
__global__ __launch_bounds__(256) void k_tr(const float* __restrict__ src, float* __restrict__ dst,
                                            int R, int C) {
  __shared__ float T[64][65];
  const int tid = threadIdx.x;
  const int c0 = blockIdx.x * 64, r0 = blockIdx.y * 64;
  const int cx = tid & 15, ry = tid >> 4;
#pragma unroll
  for (int ii = 0; ii < 4; ii++) {
    int r = ry + ii * 16;
    float4 v = *(const float4*)(src + (size_t)(r0 + r) * C + c0 + cx * 4);
    T[cx * 4 + 0][r] = v.x; T[cx * 4 + 1][r] = v.y;
    T[cx * 4 + 2][r] = v.z; T[cx * 4 + 3][r] = v.w;
  }
  __syncthreads();
#pragma unroll
  for (int ii = 0; ii < 4; ii++) {
    int c = ry + ii * 16;
    float4 v = make_float4(T[c][cx * 4], T[c][cx * 4 + 1], T[c][cx * 4 + 2], T[c][cx * 4 + 3]);
    *(float4*)(dst + (size_t)(c0 + c) * R + r0 + cx * 4) = v;
  }
}

// ---- Y[b][t][j] -> Yt[b*64+j][t] ----
__global__ __launch_bounds__(256) void k_trY(const float* __restrict__ Y, float* __restrict__ Yt) {
  __shared__ float T[64][65];
  const int tid = threadIdx.x;
  const int t0 = blockIdx.x * 64, b = blockIdx.y;
  const int cx = tid & 15, ry = tid >> 4;
#pragma unroll
  for (int ii = 0; ii < 4; ii++) {
    int r = ry + ii * 16;
    float4 v = *(const float4*)(Y + ((size_t)b * T_DIM + t0 + r) * 64 + cx * 4);
    T[cx * 4 + 0][r] = v.x; T[cx * 4 + 1][r] = v.y;
    T[cx * 4 + 2][r] = v.z; T[cx * 4 + 3][r] = v.w;
  }
  __syncthreads();
#pragma unroll
  for (int ii = 0; ii < 4; ii++) {
    int j = ry + ii * 16;
    float4 v = make_float4(T[j][cx * 4], T[j][cx * 4 + 1], T[j][cx * 4 + 2], T[j][cx * 4 + 3]);
    *(float4*)(Yt + ((size_t)b * 64 + j) * T_DIM + t0 + cx * 4) = v;
  }
}

__global__ void k_initx(float* __restrict__ X) {
  int g = blockIdx.x * 256 + threadIdx.x;
  if (g < 4096) {
    unsigned h = (unsigned)g * 2654435761u;
    h ^= h >> 16; h *= 2246822519u; h ^= h >> 13;
    X[g] = ((float)(h & 0xffffff) / 16777216.0f) - 0.5f;
  }
}

// ---- power step on f16 M: 256 blocks x 4 rows, 4 cols ----
__global__ __launch_bounds__(256) void k_matvec(const _Float16* __restrict__ M, const float* __restrict__ Xin,
                                                float* __restrict__ Xout, const float* __restrict__ prevNorm,
                                                float* __restrict__ outNorm) {
  const int tid = threadIdx.x, lane = tid & 63, w = tid >> 6;
  const int row = blockIdx.x * 4 + w;
  const _Float16* Mr = M + (size_t)row * 1024;
  float s[4] = {0.f, 0.f, 0.f, 0.f};
  for (int j = 0; j < 16; j++) {
    int k = j * 64 + lane;
    float m = (float)Mr[k];
    float4 x = *(const float4*)(Xin + k * 4);
    s[0] = fmaf(m, x.x, s[0]); s[1] = fmaf(m, x.y, s[1]);
    s[2] = fmaf(m, x.z, s[2]); s[3] = fmaf(m, x.w, s[3]);
  }
#pragma unroll
  for (int off = 32; off > 0; off >>= 1)
#pragma unroll
    for (int c = 0; c < 4; c++) s[c] += __shfl_down(s[c], off, 64);
  __shared__ float red[16];
  if (lane == 0) {
#pragma unroll
    for (int c = 0; c < 4; c++) {
      float sc = prevNorm ? rsqrtf(prevNorm[c]) : 1.0f;
      float o = s[c] * sc;
      Xout[row * 4 + c] = o;
      red[w * 4 + c] = o * o;
    }
  }
  __syncthreads();
  if (tid < 4) atomicAdd(&outNorm[tid], red[tid] + red[4 + tid] + red[8 + tid] + red[12 + tid]);
}

// ---- Rayleigh quotient vs fp32 G ----
__global__ __launch_bounds__(256) void k_rq(const float* __restrict__ G, const float* __restrict__ X,
                                            float* __restrict__ num, float* __restrict__ den) {
  const int tid = threadIdx.x, lane = tid & 63, w = tid >> 6;
  const int row = blockIdx.x * 4 + w;
  const float* Gr = G + (size_t)row * 1024;
  float s[4] = {0.f, 0.f, 0.f, 0.f};
  for (int j = 0; j < 16; j++) {
    int k = j * 64 + lane;
    float m = Gr[k];
    float4 x = *(const float4*)(X + k * 4);
    s[0] = fmaf(m, x.x, s[0]); s[1] = fmaf(m, x.y, s[1]);
    s[2] = fmaf(m, x.z, s[2]); s[3] = fmaf(m, x.w, s[3]);
  }
#pragma unroll
  for (int off = 32; off > 0; off >>= 1)
#pragma unroll
    for (int c = 0; c < 4; c++) s[c] += __shfl_down(s[c], off, 64);
  __shared__ float rn[16], rd[16];
  if (lane == 0) {
    float4 v = *(const float4*)(X + row * 4);
    float vv[4] = {v.x, v.y, v.z, v.w};
#pragma unroll
    for (int c = 0; c < 4; c++) { rn[w * 4 + c] = vv[c] * s[c]; rd[w * 4 + c] = vv[c] * vv[c]; }
  }
  __syncthreads();
  if (tid < 4) {
    atomicAdd(&num[tid], rn[tid] + rn[4 + tid] + rn[8 + tid] + rn[12 + tid]);
    atomicAdd(&den[tid], rd[tid] + rd[4 + tid] + rd[8 + tid] + rd[12 + tid]);
  }
}

__global__ void k_finL(const float* __restrict__ num, const float* __restrict__ den, float* __restrict__ Lout) {
  if (threadIdx.x == 0 && blockIdx.x == 0) {
    float best = 0.f;
    for (int c = 0; c < 4; c++) { float r = num[c] / den[c]; best = fmaxf(best, r); }
    Lout[0] = 1.0f / best;
  }
}

// rowss[n] = sum_p (1/(|Cc[n][p]|+eps))^2
__global__ __launch_bounds__(256) void k_rowss(const float* __restrict__ Cc, float* __restrict__ rowss) {
  const int n = blockIdx.x, tid = threadIdx.x;
  const float4* row = (const float4*)(Cc + (size_t)n * NP);
  float s = 0.f;
  for (int i = tid; i < 512; i += 256) {
    float4 v = row[i];
    float r0 = 1.f / (fabsf(v.x) + EPS_W), r1 = 1.f / (fabsf(v.y) + EPS_W);
    float r2 = 1.f / (fabsf(v.z) + EPS_W), r3 = 1.f / (fabsf(v.w) + EPS_W);
    s += r0 * r0 + r1 * r1 + r2 * r2 + r3 * r3;
  }
  __shared__ float red[256];
  red[tid] = s; __syncthreads();
  for (int off = 128; off > 0; off >>= 1) {
    if (tid < off) red[tid] += red[tid + off];
    __syncthreads();
  }
  if (tid == 0) rowss[n] = red[0];
}

__global__ __launch_bounds__(256) void k_thrmat(const float* __restrict__ Cc, const float* __restrict__ rowss,
                                                const float* __restrict__ Lptr, float* __restrict__ thrMat) {
  const size_t g = (size_t)blockIdx.x * 256 + threadIdx.x;
  const int n = (int)(g >> 11);
  float r = 1.0f / (fabsf(Cc[g]) + EPS_W);
  thrMat[g] = Lptr[0] * LAM0 * (float)NP * r * rsqrtf(rowss[n]);
}

// out[b][p][j] = Cc[n=b*64+j][p]
__global__ __launch_bounds__(256) void k_out(const float* __restrict__ Cc, float* __restrict__ out) {
  __shared__ float T[64][65];
  const int tid = threadIdx.x;
  const int p0 = blockIdx.x * 64, nt = blockIdx.y;
  const int pr = tid & 15, nr = tid >> 4;
#pragma unroll
  for (int ii = 0; ii < 4; ii++) {
    int n_l = nr + ii * 16;
    float4 v = *(const float4*)(Cc + ((size_t)nt * 64 + n_l) * NP + p0 + pr * 4);
    T[pr * 4 + 0][n_l] = v.x; T[pr * 4 + 1][n_l] = v.y;
    T[pr * 4 + 2][n_l] = v.z; T[pr * 4 + 3][n_l] = v.w;
  }
  __syncthreads();
#pragma unroll
  for (int ii = 0; ii < 4; ii++) {
    int p_l = nr + ii * 16;
    float4 v = make_float4(T[p_l][pr * 4], T[p_l][pr * 4 + 1], T[p_l][pr * 4 + 2], T[p_l][pr * 4 + 3]);
    *(float4*)(out + (size_t)nt * (NP * 64) + (size_t)(p0 + p_l) * 64 + pr * 4) = v;
  }
}

#define MBf(x) ((size_t)(x) * 262144)   // MB -> float count

extern "C" void kernel_launch(void* const* d_in, const int* in_sizes, int n_in,
                              void* d_out, int out_size, void* d_ws, size_t ws_size,
                              hipStream_t stream) {
  const float* Y = (const float*)d_in[0];   // [16,1024,64]
  const float* D = (const float*)d_in[1];   // [1024,2048]
  float* out = (float*)d_out;
  float* ws = (float*)d_ws;

  // ---- In-loop layout (96 MB high-water; verified overlay map) ----
  _Float16* H    = (_Float16*)(ws);                  // 0-8 MB
  _Float16* Ee   = (_Float16*)(ws + MBf(8));         // 8-16
  float*    DtY  = ws + MBf(16);                     // 16-24
  float*    Cc0  = ws + MBf(24);                     // 24-32
  float*    Cc1  = ws + MBf(32);                     // 32-40
  _Float16* Ch0  = (_Float16*)(ws + MBf(40));        // 40-44
  _Float16* Cl0  = (_Float16*)(ws + MBf(44));        // 44-48
  _Float16* Ch1  = (_Float16*)(ws + MBf(48));        // 48-52
  _Float16* Cl1  = (_Float16*)(ws + MBf(52));        // 52-56
  float*    thrM = ws + MBf(56);                     // 56-64
  float*    part = ws + MBf(64);                     // 64-96 (4 x 8 MB)
  // ---- Pre-loop-only overlays (written-before-read by in-loop owners) ----
  float*    Dt   = ws + MBf(64);                     // in part
  float*    Yt   = ws + MBf(72);                     // in part
  float*    G    = ws + MBf(76);                     // in part
  _Float16* Mh0  = (_Float16*)(ws + MBf(80));        // in part
  _Float16* Mh1  = (_Float16*)(ws + MBf(82));        // in part
  _Float16* Dh   = (_Float16*)(ws + MBf(32));        // in Cc1 (epi i=0 writes Cc1)
  _Float16* Dl   = (_Float16*)(ws + MBf(36));        // in Cc1
  _Float16* Dth  = (_Float16*)(ws + MBf(48));        // in Ch1 (epi i=0 writes Ch1)
  _Float16* Dtl  = (_Float16*)(ws + MBf(52));        // in Cl1
  _Float16* Yth  = (_Float16*)(ws + MBf(56));        // in thrM (written at i=25)
  _Float16* Ytl  = (_Float16*)(ws + MBf(58));        // in thrM
  float*    XA   = ws + MBf(96);
  float*    XB   = XA + 4096;
  float*    scal = XB + 4096;
  float*    ssv   = scal;                // [8]
  float*    norms = scal + 8;            // [NPI*4]
  float*    num   = scal + 8 + NPI * 4;  // [4]
  float*    den   = num + 4;             // [4]
  float*    Lp    = den + 4;             // [4]
  float*    rowss = Lp + 4;              // [1024]

  float*    CcB[2] = {Cc0, Cc1};
  _Float16* ChB[2] = {Ch0, Ch1};
  _Float16* ClB[2] = {Cl0, Cl1};

  hipMemsetAsync(Cc0, 0, (size_t)NB * NP * sizeof(float), stream);
  hipMemsetAsync(Ch0, 0, (size_t)2 * NB * NP * sizeof(_Float16), stream);  // Ch0+Cl0 contiguous
  hipMemsetAsync(scal, 0, (8 + NPI * 4 + 16) * sizeof(float), stream);

  k_initx<<<16, 256, 0, stream>>>(XA);
  // transposes + splits
  k_tr <<<dim3(32, 16), 256, 0, stream>>>(D, Dt, 1024, 2048);
  k_trY<<<dim3(16, 16), 256, 0, stream>>>(Y, Yt);
  k_split<<<2048, 256, 0, stream>>>(D,  Dh,  Dl,  (T_DIM * NP) / 4);
  k_split<<<2048, 256, 0, stream>>>(Dt, Dth, Dtl, (T_DIM * NP) / 4);
  k_split<<<1024, 256, 0, stream>>>(Yt, Yth, Ytl, (NB * T_DIM) / 4);
  // Gram + operator + data-term (64-tile BK=64 kernels, 4 blocks/CU)
  k_g  <<<256,  256, 0, stream>>>(Dh, Dl, G, ssv);
  k_dtd<<<1024, 256, 0, stream>>>(Dth, Dtl, H, Ee);
  k_dty<<<512,  256, 0, stream>>>(Yth, Ytl, Dth, Dtl, DtY);
  // spectral norm: 5 f16 squarings (G^32) + 8 power steps + Rayleigh on G
  k_h16<<<1024, 256, 0, stream>>>(G, Mh0, (1024 * 1024) / 4, 1.0f / 64.0f);
  _Float16* MB[2] = {Mh0, Mh1};
  for (int l = 0; l < NSQ; l++) {
    float invfac = (l == 0) ? 4096.0f : (1.0f / 16777216.0f);
    k_sqf<<<256, 256, 0, stream>>>(MB[l & 1], ssv + l, MB[(l + 1) & 1], ssv + l + 1, invfac);
  }
  _Float16* Mfin = MB[NSQ & 1];
  for (int i = 0; i < NPI; i++) {
    const float* xin = (i & 1) ? XB : XA;
    float* xout = (i & 1) ? XA : XB;
    k_matvec<<<256, 256, 0, stream>>>(Mfin, xin, xout,
                                      i ? norms + (i - 1) * 4 : nullptr, norms + i * 4);
  }
  k_rq  <<<256, 256, 0, stream>>>(G, XA, num, den);
  k_finL<<<1, 64, 0, stream>>>(num, den, Lp);

  // deterministic momentum sequence (done-flag can never trigger: ||dC||_F >> 1e-6)
  float tcv[2 * NITER];
  {
    float t = 1.0f;
    for (int i = 0; i < 2 * NITER; i++) {
      float tn = 0.5f * (1.0f + sqrtf(1.0f + 4.0f * t * t));
      tcv[i] = (t - 1.0f) / tn;
      t = tn;
    }
  }

  for (int i = 0; i < 2 * NITER; i++) {
    int a = i & 1, b = (i + 1) & 1;
    if (i == NITER) {
      k_rowss <<<1024, 256, 0, stream>>>(CcB[a], rowss);
      k_thrmat<<<(NB * NP) / 256, 256, 0, stream>>>(CcB[a], rowss, Lp, thrM);
    }
    const float* thr = (i < NITER) ? nullptr : thrM;
    k_mm <<<512, 512, 0, stream>>>(ChB[a], ClB[a], H, Ee, part);
    k_epi<<<1024, 256, 0, stream>>>(part, DtY, CcB[a], ChB[a], ClB[a], Lp, thr,
                                    tcv[i], CcB[b], ChB[b], ClB[b]);
  }
  k_out<<<dim3(32, 16), 256, 0, stream>>>(CcB[0], out);
}

// Round 11
// 3339.826 us; speedup vs baseline: 1.0758x; 1.0758x over previous
//
#include <hip/hip_runtime.h>
#include <math.h>

#define T_DIM 1024
#define NP    2048
#define NB    1024
#define NITER 25
#define NSQ   5
#define NPI   8
#define LAM0  0.1f
#define EPS_W 1e-10f

typedef float    f32x4 __attribute__((ext_vector_type(4)));
typedef _Float16 f16x8 __attribute__((ext_vector_type(8)));
typedef _Float16 f16x4 __attribute__((ext_vector_type(4)));

__device__ __forceinline__ void gload16(const void* g, void* l) {
  __builtin_amdgcn_global_load_lds((const __attribute__((address_space(1))) unsigned int*)g,
                                   (__attribute__((address_space(3))) unsigned int*)l, 16, 0, 0);
}

// =====================================================================
// Double-buffered 128x128-tile dual-acc 3-pass split-f16 core (BK=32).
// 512 thr = 8 waves (2n x 4p), wave tile 64x32. LDS 2 buf x 4 arr x 8KB = 64KB.
// (R9-proven: ~40 us/dispatch.)
// =====================================================================
__device__ __forceinline__ void mm3_db(
    const _Float16* __restrict__ Ah, const _Float16* __restrict__ Al,
    const _Float16* __restrict__ Bh, const _Float16* __restrict__ Bl,
    int ldk, int n0, int p0, int kb0, int nsteps,   // nsteps = K/32
    f32x4 acc0[4][2], f32x4 acc1[4][2])
{
  __shared__ __align__(16) _Float16 sm[2][4][4096];
  const int tid = threadIdx.x;
  const int lane = tid & 63, wave = tid >> 6;
  const int quad = lane >> 4, rl = lane & 15;
  const int wn = (wave >> 2) * 64, wp = (wave & 3) * 32;
  const int kc = tid >> 7, row = tid & 127;
  const int lbe = wave * 512;
#pragma unroll
  for (int i = 0; i < 4; i++)
#pragma unroll
    for (int j = 0; j < 2; j++) { acc0[i][j] = (f32x4)0.0f; acc1[i][j] = (f32x4)0.0f; }

  {
    size_t ga = (size_t)(n0 + row) * ldk + kb0 + kc * 8;
    size_t gb = (size_t)(p0 + row) * ldk + kb0 + kc * 8;
    gload16(Ah + ga, &sm[0][0][lbe]);
    gload16(Al + ga, &sm[0][1][lbe]);
    gload16(Bh + gb, &sm[0][2][lbe]);
    gload16(Bl + gb, &sm[0][3][lbe]);
  }
  for (int s = 0; s < nsteps; s++) {
    const int cur = s & 1;
    __syncthreads();
    if (s + 1 < nsteps) {
      const int nxt = cur ^ 1;
      const int kb = kb0 + (s + 1) * 32;
      size_t ga = (size_t)(n0 + row) * ldk + kb + kc * 8;
      size_t gb = (size_t)(p0 + row) * ldk + kb + kc * 8;
      gload16(Ah + ga, &sm[nxt][0][lbe]);
      gload16(Al + ga, &sm[nxt][1][lbe]);
      gload16(Bh + gb, &sm[nxt][2][lbe]);
      gload16(Bl + gb, &sm[nxt][3][lbe]);
    }
    f16x8 a_h[4], a_l[4], b_h[2], b_l[2];
#pragma unroll
    for (int t = 0; t < 4; t++) {
      int ar = (quad * 128 + wn + t * 16 + rl) * 8;
      a_h[t] = *(const f16x8*)&sm[cur][0][ar];
      a_l[t] = *(const f16x8*)&sm[cur][1][ar];
    }
#pragma unroll
    for (int t = 0; t < 2; t++) {
      int bp = (quad * 128 + wp + t * 16 + rl) * 8;
      b_h[t] = *(const f16x8*)&sm[cur][2][bp];
      b_l[t] = *(const f16x8*)&sm[cur][3][bp];
    }
#pragma unroll
    for (int mt = 0; mt < 4; mt++)
#pragma unroll
      for (int nt = 0; nt < 2; nt++)
        acc0[mt][nt] = __builtin_amdgcn_mfma_f32_16x16x32_f16(a_h[mt], b_h[nt], acc0[mt][nt], 0, 0, 0);
#pragma unroll
    for (int mt = 0; mt < 4; mt++)
#pragma unroll
      for (int nt = 0; nt < 2; nt++)
        acc1[mt][nt] = __builtin_amdgcn_mfma_f32_16x16x32_f16(a_l[mt], b_h[nt], acc1[mt][nt], 0, 0, 0);
#pragma unroll
    for (int mt = 0; mt < 4; mt++)
#pragma unroll
      for (int nt = 0; nt < 2; nt++)
        acc1[mt][nt] = __builtin_amdgcn_mfma_f32_16x16x32_f16(a_h[mt], b_l[nt], acc1[mt][nt], 0, 0, 0);
  }
}

// ---- main-loop GEMM: part[z] = Cp x DtD, splitK=4, XCD-swizzled ----
__global__ __launch_bounds__(512, 4) void k_mm(const _Float16* __restrict__ Ch, const _Float16* __restrict__ Cl,
                                               const _Float16* __restrict__ H, const _Float16* __restrict__ Ee,
                                               float* __restrict__ part) {
  const int b = blockIdx.x;
  const int xcd = b & 7, q = b >> 3;
  const int pt = xcd * 2 + (q & 1);
  const int ny = (q >> 1) & 7;
  const int z  = q >> 4;
  f32x4 acc0[4][2], acc1[4][2];
  const int n0 = ny * 128, p0 = pt * 128;
  mm3_db(Ch, Cl, H, Ee, 2048, n0, p0, z * 512, 16, acc0, acc1);
  const int lane = threadIdx.x & 63, wave = threadIdx.x >> 6;
  const int quad = lane >> 4, rl = lane & 15;
  const int wn = (wave >> 2) * 64, wp = (wave & 3) * 32;
  float* op = part + (size_t)z * NB * NP;
#pragma unroll
  for (int mt = 0; mt < 4; mt++)
#pragma unroll
    for (int nt = 0; nt < 2; nt++) {
      const int p = p0 + wp + nt * 16 + rl;
      const size_t rb = (size_t)(n0 + wn + mt * 16 + quad * 4) * NP + p;
#pragma unroll
      for (int r = 0; r < 4; r++)
        op[rb + (size_t)r * NP] = acc0[mt][nt][r] + acc1[mt][nt][r] * (1.f / 4096.f);
    }
}

// ---- epilogue: XCD-local block map (R9-proven, 2048 blocks x 4 elems) ----
__global__ __launch_bounds__(256) void k_epi(const float* __restrict__ part,
    const float* __restrict__ DtY_, const float* __restrict__ CcIn,
    const _Float16* __restrict__ ChIn, const _Float16* __restrict__ ClIn,
    const float* __restrict__ Lptr, const float* __restrict__ thrM, float tc,
    float* __restrict__ CcOut, _Float16* __restrict__ ChOut, _Float16* __restrict__ ClOut) {
  const int b = blockIdx.x;            // 2048 blocks
  const int xcd = b & 7, r_ = b >> 3;  // r_ 0..255
  const int pt = xcd * 2 + (r_ & 1);   // matches k_mm's pt->XCD map
  const int nc = r_ >> 1;              // 0..127
  const int tid = threadIdx.x;
  const int rowi = nc * 8 + (tid >> 5);
  const int col = pt * 128 + (tid & 31) * 4;
  const size_t g = (size_t)rowi * NP + col;
  const float Lv = Lptr[0];
  float ps[4], dy[4], cc[4], th[4];
  *(float4*)ps = *(const float4*)(part + g);
#pragma unroll
  for (int z = 1; z < 4; z++) {
    float t[4];
    *(float4*)t = *(const float4*)(part + (size_t)z * NB * NP + g);
#pragma unroll
    for (int j = 0; j < 4; j++) ps[j] += t[j];
  }
  *(float4*)dy = *(const float4*)(DtY_ + g);
  *(float4*)cc = *(const float4*)(CcIn + g);
  f16x4 chv = *(const f16x4*)(ChIn + g);
  f16x4 clv = *(const f16x4*)(ClIn + g);
  if (thrM) { *(float4*)th = *(const float4*)(thrM + g); }
  float cn[4];
  f16x4 ho, lo;
#pragma unroll
  for (int j = 0; j < 4; j++) {
    float grad = ps[j] - dy[j];
    float cp = (float)chv[j] + (float)clv[j] * (1.f / 4096.f);
    float z = cp - Lv * grad;
    float t2 = thrM ? th[j] : Lv * LAM0;
    float az = fabsf(z) - t2;
    float v = az > 0.f ? copysignf(az, z) : 0.f;
    cn[j] = v;
    float cpn = fmaf(tc, v - cc[j], v);
    _Float16 h = (_Float16)cpn;
    ho[j] = h;
    lo[j] = (_Float16)((cpn - (float)h) * 4096.f);
  }
  *(float4*)(CcOut + g) = *(float4*)cn;
  if (ChOut) {                          // skipped on the final iteration
    *(f16x4*)(ChOut + g) = ho;
    *(f16x4*)(ClOut + g) = lo;
  }
}

// ---- iteration 0 shortcut: Cp=Cc=0, tc=0  =>  v = soft(L*DtY, L*LAM0) ----
__global__ __launch_bounds__(256) void k_init0(const float* __restrict__ DtY_,
    const float* __restrict__ Lptr, float* __restrict__ CcOut,
    _Float16* __restrict__ ChOut, _Float16* __restrict__ ClOut) {
  const size_t g = ((size_t)blockIdx.x * 256 + threadIdx.x) * 4;
  const float Lv = Lptr[0];
  const float thr = Lv * LAM0;
  float dy[4];
  *(float4*)dy = *(const float4*)(DtY_ + g);
  float cn[4];
  f16x4 ho, lo;
#pragma unroll
  for (int j = 0; j < 4; j++) {
    float z = Lv * dy[j];
    float az = fabsf(z) - thr;
    float v = az > 0.f ? copysignf(az, z) : 0.f;
    cn[j] = v;
    _Float16 h = (_Float16)v;
    ho[j] = h;
    lo[j] = (_Float16)((v - (float)h) * 4096.f);
  }
  *(float4*)(CcOut + g) = *(float4*)cn;
  *(f16x4*)(ChOut + g) = ho;
  *(f16x4*)(ClOut + g) = lo;
}

// =====================================================================
// 64x64-tile core for the fast pre-loop kernels (R8/R9-proven, BK=128).
// =====================================================================
__device__ __forceinline__ void mm3c(
    const _Float16* __restrict__ Ah, const _Float16* __restrict__ Al,
    const _Float16* __restrict__ Bh, const _Float16* __restrict__ Bl,
    int ldk, int n0, int p0, int nsteps,            // nsteps = K/128
    f32x4 acc0[2][2], f32x4 acc1[2][2])
{
  __shared__ __align__(16) _Float16 sAh[8192], sAl[8192], sBh[8192], sBl[8192];
  const int tid = threadIdx.x;
  const int lane = tid & 63, w = tid >> 6;
  const int quad = lane >> 4, rl = lane & 15;
  const int wm = (w >> 1) * 32, wp = (w & 1) * 32;
#pragma unroll
  for (int i = 0; i < 2; i++)
#pragma unroll
    for (int j = 0; j < 2; j++) { acc0[i][j] = (f32x4)0.0f; acc1[i][j] = (f32x4)0.0f; }

  for (int s = 0; s < nsteps; s++) {
    const int kb = s * 128;
    if (s) __syncthreads();
#pragma unroll
    for (int i = 0; i < 4; i++) {
      int slot = i * 256 + w * 64 + lane;
      int kc = slot >> 6, row = slot & 63;
      int lb = (i * 256 + w * 64) * 8;
      size_t ga = (size_t)(n0 + row) * ldk + kb + kc * 8;
      size_t gb = (size_t)(p0 + row) * ldk + kb + kc * 8;
      gload16(Ah + ga, sAh + lb);
      gload16(Al + ga, sAl + lb);
      gload16(Bh + gb, sBh + lb);
      gload16(Bl + gb, sBl + lb);
    }
    __syncthreads();
#pragma unroll
    for (int kk = 0; kk < 4; kk++) {
      const int kc = kk * 4 + quad;
      f16x8 a_h[2], a_l[2], b_h[2], b_l[2];
#pragma unroll
      for (int t = 0; t < 2; t++) {
        int ar = wm + t * 16 + rl;
        int bp = wp + t * 16 + rl;
        a_h[t] = *(const f16x8*)&sAh[(kc * 64 + ar) * 8];
        a_l[t] = *(const f16x8*)&sAl[(kc * 64 + ar) * 8];
        b_h[t] = *(const f16x8*)&sBh[(kc * 64 + bp) * 8];
        b_l[t] = *(const f16x8*)&sBl[(kc * 64 + bp) * 8];
      }
#pragma unroll
      for (int mt = 0; mt < 2; mt++)
#pragma unroll
        for (int nt = 0; nt < 2; nt++) {
          acc0[mt][nt] = __builtin_amdgcn_mfma_f32_16x16x32_f16(a_h[mt], b_h[nt], acc0[mt][nt], 0, 0, 0);
          acc1[mt][nt] = __builtin_amdgcn_mfma_f32_16x16x32_f16(a_l[mt], b_h[nt], acc1[mt][nt], 0, 0, 0);
          acc1[mt][nt] = __builtin_amdgcn_mfma_f32_16x16x32_f16(a_h[mt], b_l[nt], acc1[mt][nt], 0, 0, 0);
        }
    }
  }
}

// ---- DtD (2048x2048, K=1024): emits H/Ee split. grid 1024. ----
__global__ __launch_bounds__(256, 2) void k_dtd(const _Float16* __restrict__ Dth, const _Float16* __restrict__ Dtl,
                                                _Float16* __restrict__ H, _Float16* __restrict__ Ee) {
  const int b = blockIdx.x;
  const int xcd = b & 7, i4 = b >> 3;
  const int ny = i4 >> 2, pt = xcd * 4 + (i4 & 3);
  const int n0 = ny * 64, p0 = pt * 64;
  f32x4 acc0[2][2], acc1[2][2];
  mm3c(Dth, Dtl, Dth, Dtl, 1024, n0, p0, 8, acc0, acc1);
  const int lane = threadIdx.x & 63, w = threadIdx.x >> 6;
  const int quad = lane >> 4, rl = lane & 15;
  const int wm = (w >> 1) * 32, wp = (w & 1) * 32;
#pragma unroll
  for (int mt = 0; mt < 2; mt++)
#pragma unroll
    for (int nt = 0; nt < 2; nt++) {
      const int p = p0 + wp + nt * 16 + rl;
      const size_t rb = (size_t)(n0 + wm + mt * 16 + quad * 4) * NP + p;
#pragma unroll
      for (int r = 0; r < 4; r++) {
        const size_t idx = rb + (size_t)r * NP;
        float v = acc0[mt][nt][r] + acc1[mt][nt][r] * (1.f / 4096.f);
        _Float16 h = (_Float16)v;
        H[idx] = h;
        Ee[idx] = (_Float16)((v - (float)h) * 4096.f);
      }
    }
}

// ---- G = D x D^T (1024x1024, K=2048) fp32 + ||G||_F^2. grid 256. ----
__global__ __launch_bounds__(256, 2) void k_g(const _Float16* __restrict__ Dh, const _Float16* __restrict__ Dl,
                                              float* __restrict__ G, float* __restrict__ ss0) {
  const int b = blockIdx.x;
  const int xcd = b & 7, i4 = b >> 3;
  const int ny = i4 >> 1, pt = xcd * 2 + (i4 & 1);
  const int n0 = ny * 64, p0 = pt * 64;
  f32x4 acc0[2][2], acc1[2][2];
  mm3c(Dh, Dl, Dh, Dl, 2048, n0, p0, 16, acc0, acc1);
  const int tid = threadIdx.x;
  const int lane = tid & 63, w = tid >> 6;
  const int quad = lane >> 4, rl = lane & 15;
  const int wm = (w >> 1) * 32, wp = (w & 1) * 32;
  float ssl = 0.f;
#pragma unroll
  for (int mt = 0; mt < 2; mt++)
#pragma unroll
    for (int nt = 0; nt < 2; nt++) {
      const int p = p0 + wp + nt * 16 + rl;
      const size_t rb = (size_t)(n0 + wm + mt * 16 + quad * 4) * 1024 + p;
#pragma unroll
      for (int r = 0; r < 4; r++) {
        float v = acc0[mt][nt][r] + acc1[mt][nt][r] * (1.f / 4096.f);
        G[rb + (size_t)r * 1024] = v;
        ssl = fmaf(v, v, ssl);
      }
    }
  __shared__ float red[256];
  red[tid] = ssl; __syncthreads();
  for (int off = 128; off > 0; off >>= 1) {
    if (tid < off) red[tid] += red[tid + off];
    __syncthreads();
  }
  if (tid == 0) atomicAdd(ss0, red[0]);
}

// ---- DtY[n][p] (1024x2048, K=1024) fp32. grid 512. ----
__global__ __launch_bounds__(256, 2) void k_dty(const _Float16* __restrict__ Yth, const _Float16* __restrict__ Ytl,
                                                const _Float16* __restrict__ Dth, const _Float16* __restrict__ Dtl,
                                                float* __restrict__ DtY_) {
  const int b = blockIdx.x;
  const int xcd = b & 7, i4 = b >> 3;
  const int ny = i4 >> 2, pt = xcd * 4 + (i4 & 3);
  const int n0 = ny * 64, p0 = pt * 64;
  f32x4 acc0[2][2], acc1[2][2];
  mm3c(Yth, Ytl, Dth, Dtl, 1024, n0, p0, 8, acc0, acc1);
  const int lane = threadIdx.x & 63, w = threadIdx.x >> 6;
  const int quad = lane >> 4, rl = lane & 15;
  const int wm = (w >> 1) * 32, wp = (w & 1) * 32;
#pragma unroll
  for (int mt = 0; mt < 2; mt++)
#pragma unroll
    for (int nt = 0; nt < 2; nt++) {
      const int p = p0 + wp + nt * 16 + rl;
      const size_t rb = (size_t)(n0 + wm + mt * 16 + quad * 4) * NP + p;
#pragma unroll
      for (int r = 0; r < 4; r++)
        DtY_[rb + (size_t)r * NP] = acc0[mt][nt][r] + acc1[mt][nt][r] * (1.f / 4096.f);
    }
}

// ---- f16 squaring, fused normalize + x4096 lift + f16 out. grid 256. ----
__global__ __launch_bounds__(256, 2) void k_sqf(const _Float16* __restrict__ Min, const float* __restrict__ ssPrev,
                                                _Float16* __restrict__ Mout, float* __restrict__ ssNext,
                                                float invfac) {
  __shared__ __align__(16) _Float16 sA[8192], sB[8192];
  const int b = blockIdx.x;
  const int xcd = b & 7, i4 = b >> 3;
  const int ny = i4 >> 1, pt = xcd * 2 + (i4 & 1);
  const int n0 = ny * 64, p0 = pt * 64;
  const int tid = threadIdx.x;
  const int lane = tid & 63, w = tid >> 6;
  const int quad = lane >> 4, rl = lane & 15;
  const int wm = (w >> 1) * 32, wp = (w & 1) * 32;
  f32x4 acc[2][2];
#pragma unroll
  for (int i = 0; i < 2; i++)
#pragma unroll
    for (int j = 0; j < 2; j++) acc[i][j] = (f32x4)0.0f;

  for (int s = 0; s < 8; s++) {
    const int kb = s * 128;
    if (s) __syncthreads();
#pragma unroll
    for (int i = 0; i < 4; i++) {
      int slot = i * 256 + w * 64 + lane;
      int kc = slot >> 6, row = slot & 63;
      int lb = (i * 256 + w * 64) * 8;
      gload16(Min + (size_t)(n0 + row) * 1024 + kb + kc * 8, sA + lb);
      gload16(Min + (size_t)(p0 + row) * 1024 + kb + kc * 8, sB + lb);
    }
    __syncthreads();
#pragma unroll
    for (int kk = 0; kk < 4; kk++) {
      const int kc = kk * 4 + quad;
      f16x8 a[2], bb[2];
#pragma unroll
      for (int t = 0; t < 2; t++) {
        a[t]  = *(const f16x8*)&sA[(kc * 64 + wm + t * 16 + rl) * 8];
        bb[t] = *(const f16x8*)&sB[(kc * 64 + wp + t * 16 + rl) * 8];
      }
#pragma unroll
      for (int mt = 0; mt < 2; mt++)
#pragma unroll
        for (int nt = 0; nt < 2; nt++)
          acc[mt][nt] = __builtin_amdgcn_mfma_f32_16x16x32_f16(a[mt], bb[nt], acc[mt][nt], 0, 0, 0);
    }
  }
  const float inv = invfac / ssPrev[0];
  float ssl = 0.f;
#pragma unroll
  for (int mt = 0; mt < 2; mt++)
#pragma unroll
    for (int nt = 0; nt < 2; nt++) {
      const int p = p0 + wp + nt * 16 + rl;
      const size_t rb = (size_t)(n0 + wm + mt * 16 + quad * 4) * 1024 + p;
#pragma unroll
      for (int r = 0; r < 4; r++) {
        float v = acc[mt][nt][r] * inv;
        Mout[rb + (size_t)r * 1024] = (_Float16)(v * 4096.f);
        ssl = fmaf(v, v, ssl);
      }
    }
  __syncthreads();
  float* red = (float*)sA;
  red[tid] = ssl; __syncthreads();
  for (int off = 128; off > 0; off >>= 1) {
    if (tid < off) red[tid] += red[tid + off];
    __syncthreads();
  }
  if (tid == 0) atomicAdd(ssNext, red[0]);
}

// ---- fp32 -> f16 (h, l*4096) split ----
__global__ __launch_bounds__(256) void k_split(const float* __restrict__ src, _Float16* __restrict__ H,
                                               _Float16* __restrict__ L, int n4) {
  int g = blockIdx.x * 256 + threadIdx.x;
  if (g < n4) {
    float4 v = ((const float4*)src)[g];
    float vv[4] = {v.x, v.y, v.z, v.w};
    f16x4 h, l;
#pragma unroll
    for (int j = 0; j < 4; j++) {
      _Float16 hh = (_Float16)vv[j];
      h[j] = hh;
      l[j] = (_Float16)((vv[j] - (float)hh) * 4096.f);
    }
    ((f16x4*)H)[g] = h;
    ((f16x4*)L)[g] = l;
  }
}

// ---- fp32 -> f16 with scale ----
__global__ __launch_bounds__(256) void k_h16(const float* __restrict__ src, _Float16* __restrict__ dst,
                                             int n4, float scale) {
  int g = blockIdx.x * 256 + threadIdx.x;
  if (g < n4) {
    float4 v = ((const float4*)src)[g];
    f16x4 h;
    h[0] = (_Float16)(v.x * scale); h[1] = (_Float16)(v.y * scale);
    h[2] = (_Float16)(v.z * scale); h[3] = (_Float16)(v.w * scale);
    ((f16x4*)dst)[g] = h;
  }
}

// ---- fp32 transpose 64x64 tiles ----
__global__ __launch_bounds__(256) void k_tr(const float* __restrict__ src, float* __restrict__ dst,
                                            int R, int C) {
  __shared__ float T[64][65];
  const int tid = threadIdx.x;
  const int c0 = blockIdx.x * 64, r0 = blockIdx.y * 64;
  const int cx = tid & 15, ry = tid >> 4;
#pragma unroll
  for (int ii = 0; ii < 4; ii++) {
    int r = ry + ii * 16;
    float4 v = *(const float4*)(src + (size_t)(r0 + r) * C + c0 + cx * 4);
    T[cx * 4 + 0][r] = v.x; T[cx * 4 + 1][r] = v.y;
    T[cx * 4 + 2][r] = v.z; T[cx * 4 + 3][r] = v.w;
  }
  __syncthreads();
#pragma unroll
  for (int ii = 0; ii < 4; ii++) {
    int c = ry + ii * 16;
    float4 v = make_float4(T[c][cx * 4], T[c][cx * 4 + 1], T[c][cx * 4 + 2], T[c][cx * 4 + 3]);
    *(float4*)(dst + (size_t)(c0 + c) * R + r0 + cx * 4) = v;
  }
}

// ---- Y[b][t][j] -> Yt[b*64+j][t] ----
__global__ __launch_bounds__(256) void k_trY(const float* __restrict__ Y, float* __restrict__ Yt) {
  __shared__ float T[64][65];
  const int tid = threadIdx.x;
  const int t0 = blockIdx.x * 64, b = blockIdx.y;
  const int cx = tid & 15, ry = tid >> 4;
#pragma unroll
  for (int ii = 0; ii < 4; ii++) {
    int r = ry + ii * 16;
    float4 v = *(const float4*)(Y + ((size_t)b * T_DIM + t0 + r) * 64 + cx * 4);
    T[cx * 4 + 0][r] = v.x; T[cx * 4 + 1][r] = v.y;
    T[cx * 4 + 2][r] = v.z; T[cx * 4 + 3][r] = v.w;
  }
  __syncthreads();
#pragma unroll
  for (int ii = 0; ii < 4; ii++) {
    int j = ry + ii * 16;
    float4 v = make_float4(T[j][cx * 4], T[j][cx * 4 + 1], T[j][cx * 4 + 2], T[j][cx * 4 + 3]);
    *(float4*)(Yt + ((size_t)b * 64 + j) * T_DIM + t0 + cx * 4) = v;
  }
}

__global__ void k_initx(float* __restrict__ X) {
  int g = blockIdx.x * 256 + threadIdx.x;
  if (g < 4096) {
    unsigned h = (unsigned)g * 2654435761u;
    h ^= h >> 16; h *= 2246822519u; h ^= h >> 13;
    X[g] = ((float)(h & 0xffffff) / 16777216.0f) - 0.5f;
  }
}

// ---- power step on f16 M: 256 blocks x 4 rows, 4 cols ----
__global__ __launch_bounds__(256) void k_matvec(const _Float16* __restrict__ M, const float* __restrict__ Xin,
                                                float* __restrict__ Xout, const float* __restrict__ prevNorm,
                                                float* __restrict__ outNorm) {
  const int tid = threadIdx.x, lane = tid & 63, w = tid >> 6;
  const int row = blockIdx.x * 4 + w;
  const _Float16* Mr = M + (size_t)row * 1024;
  float s[4] = {0.f, 0.f, 0.f, 0.f};
  for (int j = 0; j < 16; j++) {
    int k = j * 64 + lane;
    float m = (float)Mr[k];
    float4 x = *(const float4*)(Xin + k * 4);
    s[0] = fmaf(m, x.x, s[0]); s[1] = fmaf(m, x.y, s[1]);
    s[2] = fmaf(m, x.z, s[2]); s[3] = fmaf(m, x.w, s[3]);
  }
#pragma unroll
  for (int off = 32; off > 0; off >>= 1)
#pragma unroll
    for (int c = 0; c < 4; c++) s[c] += __shfl_down(s[c], off, 64);
  __shared__ float red[16];
  if (lane == 0) {
#pragma unroll
    for (int c = 0; c < 4; c++) {
      float sc = prevNorm ? rsqrtf(prevNorm[c]) : 1.0f;
      float o = s[c] * sc;
      Xout[row * 4 + c] = o;
      red[w * 4 + c] = o * o;
    }
  }
  __syncthreads();
  if (tid < 4) atomicAdd(&outNorm[tid], red[tid] + red[4 + tid] + red[8 + tid] + red[12 + tid]);
}

// ---- Rayleigh quotient vs fp32 G ----
__global__ __launch_bounds__(256) void k_rq(const float* __restrict__ G, const float* __restrict__ X,
                                            float* __restrict__ num, float* __restrict__ den) {
  const int tid = threadIdx.x, lane = tid & 63, w = tid >> 6;
  const int row = blockIdx.x * 4 + w;
  const float* Gr = G + (size_t)row * 1024;
  float s[4] = {0.f, 0.f, 0.f, 0.f};
  for (int j = 0; j < 16; j++) {
    int k = j * 64 + lane;
    float m = Gr[k];
    float4 x = *(const float4*)(X + k * 4);
    s[0] = fmaf(m, x.x, s[0]); s[1] = fmaf(m, x.y, s[1]);
    s[2] = fmaf(m, x.z, s[2]); s[3] = fmaf(m, x.w, s[3]);
  }
#pragma unroll
  for (int off = 32; off > 0; off >>= 1)
#pragma unroll
    for (int c = 0; c < 4; c++) s[c] += __shfl_down(s[c], off, 64);
  __shared__ float rn[16], rd[16];
  if (lane == 0) {
    float4 v = *(const float4*)(X + row * 4);
    float vv[4] = {v.x, v.y, v.z, v.w};
#pragma unroll
    for (int c = 0; c < 4; c++) { rn[w * 4 + c] = vv[c] * s[c]; rd[w * 4 + c] = vv[c] * vv[c]; }
  }
  __syncthreads();
  if (tid < 4) {
    atomicAdd(&num[tid], rn[tid] + rn[4 + tid] + rn[8 + tid] + rn[12 + tid]);
    atomicAdd(&den[tid], rd[tid] + rd[4 + tid] + rd[8 + tid] + rd[12 + tid]);
  }
}

__global__ void k_finL(const float* __restrict__ num, const float* __restrict__ den, float* __restrict__ Lout) {
  if (threadIdx.x == 0 && blockIdx.x == 0) {
    float best = 0.f;
    for (int c = 0; c < 4; c++) { float r = num[c] / den[c]; best = fmaxf(best, r); }
    Lout[0] = 1.0f / best;
  }
}

// rowss[n] = sum_p (1/(|Cc[n][p]|+eps))^2
__global__ __launch_bounds__(256) void k_rowss(const float* __restrict__ Cc, float* __restrict__ rowss) {
  const int n = blockIdx.x, tid = threadIdx.x;
  const float4* row = (const float4*)(Cc + (size_t)n * NP);
  float s = 0.f;
  for (int i = tid; i < 512; i += 256) {
    float4 v = row[i];
    float r0 = 1.f / (fabsf(v.x) + EPS_W), r1 = 1.f / (fabsf(v.y) + EPS_W);
    float r2 = 1.f / (fabsf(v.z) + EPS_W), r3 = 1.f / (fabsf(v.w) + EPS_W);
    s += r0 * r0 + r1 * r1 + r2 * r2 + r3 * r3;
  }
  __shared__ float red[256];
  red[tid] = s; __syncthreads();
  for (int off = 128; off > 0; off >>= 1) {
    if (tid < off) red[tid] += red[tid + off];
    __syncthreads();
  }
  if (tid == 0) rowss[n] = red[0];
}

__global__ __launch_bounds__(256) void k_thrmat(const float* __restrict__ Cc, const float* __restrict__ rowss,
                                                const float* __restrict__ Lptr, float* __restrict__ thrMat) {
  const size_t g = (size_t)blockIdx.x * 256 + threadIdx.x;
  const int n = (int)(g >> 11);
  float r = 1.0f / (fabsf(Cc[g]) + EPS_W);
  thrMat[g] = Lptr[0] * LAM0 * (float)NP * r * rsqrtf(rowss[n]);
}

// out[b][p][j] = Cc[n=b*64+j][p]
__global__ __launch_bounds__(256) void k_out(const float* __restrict__ Cc, float* __restrict__ out) {
  __shared__ float T[64][65];
  const int tid = threadIdx.x;
  const int p0 = blockIdx.x * 64, nt = blockIdx.y;
  const int pr = tid & 15, nr = tid >> 4;
#pragma unroll
  for (int ii = 0; ii < 4; ii++) {
    int n_l = nr + ii * 16;
    float4 v = *(const float4*)(Cc + ((size_t)nt * 64 + n_l) * NP + p0 + pr * 4);
    T[pr * 4 + 0][n_l] = v.x; T[pr * 4 + 1][n_l] = v.y;
    T[pr * 4 + 2][n_l] = v.z; T[pr * 4 + 3][n_l] = v.w;
  }
  __syncthreads();
#pragma unroll
  for (int ii = 0; ii < 4; ii++) {
    int p_l = nr + ii * 16;
    float4 v = make_float4(T[p_l][pr * 4], T[p_l][pr * 4 + 1], T[p_l][pr * 4 + 2], T[p_l][pr * 4 + 3]);
    *(float4*)(out + (size_t)nt * (NP * 64) + (size_t)(p0 + p_l) * 64 + pr * 4) = v;
  }
}

#define MBf(x) ((size_t)(x) * 262144)   // MB -> float count

extern "C" void kernel_launch(void* const* d_in, const int* in_sizes, int n_in,
                              void* d_out, int out_size, void* d_ws, size_t ws_size,
                              hipStream_t stream) {
  const float* Y = (const float*)d_in[0];   // [16,1024,64]
  const float* D = (const float*)d_in[1];   // [1024,2048]
  float* out = (float*)d_out;
  float* ws = (float*)d_ws;

  // ---- In-loop layout (96 MB high-water; verified overlay map) ----
  _Float16* H    = (_Float16*)(ws);                  // 0-8 MB
  _Float16* Ee   = (_Float16*)(ws + MBf(8));         // 8-16
  float*    DtY  = ws + MBf(16);                     // 16-24
  float*    Cc0  = ws + MBf(24);                     // 24-32
  float*    Cc1  = ws + MBf(32);                     // 32-40
  _Float16* Ch0  = (_Float16*)(ws + MBf(40));        // 40-44
  _Float16* Cl0  = (_Float16*)(ws + MBf(44));        // 44-48
  _Float16* Ch1  = (_Float16*)(ws + MBf(48));        // 48-52
  _Float16* Cl1  = (_Float16*)(ws + MBf(52));        // 52-56
  float*    thrM = ws + MBf(56);                     // 56-64
  float*    part = ws + MBf(64);                     // 64-96 (4 x 8 MB)
  // ---- Pre-loop-only overlays (written-before-read by in-loop owners) ----
  float*    Dt   = ws + MBf(64);                     // in part
  float*    Yt   = ws + MBf(72);                     // in part
  float*    G    = ws + MBf(76);                     // in part
  _Float16* Mh0  = (_Float16*)(ws + MBf(80));        // in part
  _Float16* Mh1  = (_Float16*)(ws + MBf(82));        // in part
  _Float16* Dh   = (_Float16*)(ws + MBf(32));        // in Cc1 (k_init0 writes Cc1 after k_g)
  _Float16* Dl   = (_Float16*)(ws + MBf(36));        // in Cc1
  _Float16* Dth  = (_Float16*)(ws + MBf(48));        // in Ch1 (k_init0 writes Ch1 after k_dtd/k_dty)
  _Float16* Dtl  = (_Float16*)(ws + MBf(52));        // in Cl1
  _Float16* Yth  = (_Float16*)(ws + MBf(56));        // in thrM (written at i=25)
  _Float16* Ytl  = (_Float16*)(ws + MBf(58));        // in thrM
  float*    XA   = ws + MBf(96);
  float*    XB   = XA + 4096;
  float*    scal = XB + 4096;
  float*    ssv   = scal;                // [8]
  float*    norms = scal + 8;            // [NPI*4]
  float*    num   = scal + 8 + NPI * 4;  // [4]
  float*    den   = num + 4;             // [4]
  float*    Lp    = den + 4;             // [4]
  float*    rowss = Lp + 4;              // [1024]

  float*    CcB[2] = {Cc0, Cc1};
  _Float16* ChB[2] = {Ch0, Ch1};
  _Float16* ClB[2] = {Cl0, Cl1};

  hipMemsetAsync(scal, 0, (8 + NPI * 4 + 16) * sizeof(float), stream);

  k_initx<<<16, 256, 0, stream>>>(XA);
  // transposes + splits
  k_tr <<<dim3(32, 16), 256, 0, stream>>>(D, Dt, 1024, 2048);
  k_trY<<<dim3(16, 16), 256, 0, stream>>>(Y, Yt);
  k_split<<<2048, 256, 0, stream>>>(D,  Dh,  Dl,  (T_DIM * NP) / 4);
  k_split<<<2048, 256, 0, stream>>>(Dt, Dth, Dtl, (T_DIM * NP) / 4);
  k_split<<<1024, 256, 0, stream>>>(Yt, Yth, Ytl, (NB * T_DIM) / 4);
  // Gram + operator + data-term (64-tile kernels)
  k_g  <<<256,  256, 0, stream>>>(Dh, Dl, G, ssv);
  k_dtd<<<1024, 256, 0, stream>>>(Dth, Dtl, H, Ee);
  k_dty<<<512,  256, 0, stream>>>(Yth, Ytl, Dth, Dtl, DtY);
  // spectral norm: 5 f16 squarings (G^32) + 8 power steps + Rayleigh on G
  k_h16<<<1024, 256, 0, stream>>>(G, Mh0, (1024 * 1024) / 4, 1.0f / 64.0f);
  _Float16* MB[2] = {Mh0, Mh1};
  for (int l = 0; l < NSQ; l++) {
    float invfac = (l == 0) ? 4096.0f : (1.0f / 16777216.0f);
    k_sqf<<<256, 256, 0, stream>>>(MB[l & 1], ssv + l, MB[(l + 1) & 1], ssv + l + 1, invfac);
  }
  _Float16* Mfin = MB[NSQ & 1];
  for (int i = 0; i < NPI; i++) {
    const float* xin = (i & 1) ? XB : XA;
    float* xout = (i & 1) ? XA : XB;
    k_matvec<<<256, 256, 0, stream>>>(Mfin, xin, xout,
                                      i ? norms + (i - 1) * 4 : nullptr, norms + i * 4);
  }
  k_rq  <<<256, 256, 0, stream>>>(G, XA, num, den);
  k_finL<<<1, 64, 0, stream>>>(num, den, Lp);

  // deterministic momentum sequence (done-flag can never trigger: ||dC||_F >> 1e-6)
  float tcv[2 * NITER];
  {
    float t = 1.0f;
    for (int i = 0; i < 2 * NITER; i++) {
      float tn = 0.5f * (1.0f + sqrtf(1.0f + 4.0f * t * t));
      tcv[i] = (t - 1.0f) / tn;
      t = tn;
    }
  }

  // iteration 0: Cp=Cc=0, tc=0  ->  elementwise shortcut writes buffer 1
  k_init0<<<(NB * NP) / 1024, 256, 0, stream>>>(DtY, Lp, Cc1, Ch1, Cl1);

  for (int i = 1; i < 2 * NITER; i++) {
    int a = i & 1, b = (i + 1) & 1;
    if (i == NITER) {
      k_rowss <<<1024, 256, 0, stream>>>(CcB[a], rowss);
      k_thrmat<<<(NB * NP) / 256, 256, 0, stream>>>(CcB[a], rowss, Lp, thrM);
    }
    const float* thr = (i < NITER) ? nullptr : thrM;
    const bool last = (i == 2 * NITER - 1);
    k_mm <<<512, 512, 0, stream>>>(ChB[a], ClB[a], H, Ee, part);
    k_epi<<<2048, 256, 0, stream>>>(part, DtY, CcB[a], ChB[a], ClB[a], Lp, thr,
                                    tcv[i], CcB[b],
                                    last ? nullptr : ChB[b], last ? nullptr : ClB[b]);
  }
  k_out<<<dim3(32, 16), 256, 0, stream>>>(CcB[0], out);
}